// Round 9
// baseline (1062.494 us; speedup 1.0000x reference)
//
#include <hip/hip_runtime.h>

#define D_DIM 128
#define SLOT_CAP 128

typedef float f4_t __attribute__((ext_vector_type(4)));

// Plain (L2-allocating) load. A/B vs round 8: the ONLY change this round is
// dropping __builtin_nontemporal_load on the x reads — testing whether NT
// requests were bypassing L2 burst-coalescing and degrading random-512B BW.
__device__ __forceinline__ f4_t ld4(const float* p) {
  return *reinterpret_cast<const f4_t*>(p);
}

// ---------------------------------------------------------------------------
// K1: single-pass scatter into fixed-capacity per-segment slot lists.
// ---------------------------------------------------------------------------
__global__ __launch_bounds__(256) void scatter_slots_kernel(
    const int4* __restrict__ idx4,
    int* __restrict__ fill,         // [S]
    int* __restrict__ slots,        // [S*SLOT_CAP]
    int* __restrict__ ov_count,
    int* __restrict__ ovs, int* __restrict__ ovr,
    int n4) {
  int stride = gridDim.x * blockDim.x;
  for (int i = blockIdx.x * blockDim.x + threadIdx.x; i < n4; i += stride) {
    int4 v = idx4[i];
    int r = i * 4;
    int p0 = atomicAdd(&fill[v.x], 1);
    int p1 = atomicAdd(&fill[v.y], 1);
    int p2 = atomicAdd(&fill[v.z], 1);
    int p3 = atomicAdd(&fill[v.w], 1);
    if (p0 < SLOT_CAP) slots[v.x * SLOT_CAP + p0] = r;
    else { int o = atomicAdd(ov_count, 1); ovs[o] = v.x; ovr[o] = r; }
    if (p1 < SLOT_CAP) slots[v.y * SLOT_CAP + p1] = r + 1;
    else { int o = atomicAdd(ov_count, 1); ovs[o] = v.y; ovr[o] = r + 1; }
    if (p2 < SLOT_CAP) slots[v.z * SLOT_CAP + p2] = r + 2;
    else { int o = atomicAdd(ov_count, 1); ovs[o] = v.z; ovr[o] = r + 2; }
    if (p3 < SLOT_CAP) slots[v.w * SLOT_CAP + p3] = r + 3;
    else { int o = atomicAdd(ov_count, 1); ovs[o] = v.w; ovr[o] = r + 3; }
  }
}

// ---------------------------------------------------------------------------
// K2: gather-reduce. One wave owns 4 CONTIGUOUS segments.
// 32-row double-groups: 16 float4 loads in flight, two independent
// accumulators; then one 16-row group; then predicated 8-row tail.
// ---------------------------------------------------------------------------
__global__ __launch_bounds__(256, 5) void gather_reduce_kernel(
    const float* __restrict__ x,
    const int* __restrict__ slots,
    const int* __restrict__ fill,
    float* __restrict__ pooled,      // [S,128]
    int S) {
  __shared__ int ridbuf[4][4 * SLOT_CAP];  // 8 KB
  int t = threadIdx.x;
  int lane = t & 63;
  int wv = t >> 6;
  int half = lane >> 5;
  int coff = (lane & 31) << 2;
  int s0 = (blockIdx.x * 4 + wv) * 4;
  if (s0 >= S) return;

  int c0, c1, c2, c3;
  if (s0 + 3 < S) {
    int4 f = *reinterpret_cast<const int4*>(fill + s0);
    c0 = min(f.x, SLOT_CAP); c1 = min(f.y, SLOT_CAP);
    c2 = min(f.z, SLOT_CAP); c3 = min(f.w, SLOT_CAP);
    int4* rb4 = reinterpret_cast<int4*>(ridbuf[wv]);
    const int4* sp4 = reinterpret_cast<const int4*>(slots) + s0 * (SLOT_CAP / 4);
    rb4[lane] = sp4[lane];
    rb4[lane + 64] = sp4[lane + 64];
  } else {
    c0 = (s0 + 0 < S) ? min(fill[s0 + 0], SLOT_CAP) : 0;
    c1 = (s0 + 1 < S) ? min(fill[s0 + 1], SLOT_CAP) : 0;
    c2 = (s0 + 2 < S) ? min(fill[s0 + 2], SLOT_CAP) : 0;
    c3 = (s0 + 3 < S) ? min(fill[s0 + 3], SLOT_CAP) : 0;
    for (int g = 0; g < 4; ++g) {
      int c = g == 0 ? c0 : g == 1 ? c1 : g == 2 ? c2 : c3;
      if (s0 + g < S) {
        const int* sp = slots + (long long)(s0 + g) * SLOT_CAP;
        if (lane < c) ridbuf[wv][g * SLOT_CAP + lane] = sp[lane];
        if (lane + 64 < c) ridbuf[wv][g * SLOT_CAP + lane + 64] = sp[lane + 64];
      }
    }
  }

#define DO_SEG(G, CG)                                                        \
  {                                                                          \
    f4_t acc = {0.f, 0.f, 0.f, 0.f};                                         \
    f4_t acc2 = {0.f, 0.f, 0.f, 0.f};                                        \
    int full32 = CG & ~31;                                                   \
    for (int base = 0; base < full32; base += 32) {                          \
      f4_t v0, v1, v2, v3, v4, v5, v6, v7;                                   \
      f4_t w0, w1, w2, w3, w4, w5, w6, w7;                                   \
      const int* rb = &ridbuf[wv][(G) * SLOT_CAP + base + half];             \
      v0 = ld4(x + ((long long)rb[0] << 7) + coff);                          \
      v1 = ld4(x + ((long long)rb[2] << 7) + coff);                          \
      v2 = ld4(x + ((long long)rb[4] << 7) + coff);                          \
      v3 = ld4(x + ((long long)rb[6] << 7) + coff);                          \
      v4 = ld4(x + ((long long)rb[8] << 7) + coff);                          \
      v5 = ld4(x + ((long long)rb[10] << 7) + coff);                         \
      v6 = ld4(x + ((long long)rb[12] << 7) + coff);                         \
      v7 = ld4(x + ((long long)rb[14] << 7) + coff);                         \
      w0 = ld4(x + ((long long)rb[16] << 7) + coff);                         \
      w1 = ld4(x + ((long long)rb[18] << 7) + coff);                         \
      w2 = ld4(x + ((long long)rb[20] << 7) + coff);                         \
      w3 = ld4(x + ((long long)rb[22] << 7) + coff);                         \
      w4 = ld4(x + ((long long)rb[24] << 7) + coff);                         \
      w5 = ld4(x + ((long long)rb[26] << 7) + coff);                         \
      w6 = ld4(x + ((long long)rb[28] << 7) + coff);                         \
      w7 = ld4(x + ((long long)rb[30] << 7) + coff);                         \
      acc += v0; acc += v1; acc += v2; acc += v3;                            \
      acc += v4; acc += v5; acc += v6; acc += v7;                            \
      acc2 += w0; acc2 += w1; acc2 += w2; acc2 += w3;                        \
      acc2 += w4; acc2 += w5; acc2 += w6; acc2 += w7;                        \
    }                                                                        \
    int base = full32;                                                       \
    int rem = CG - full32;                                                   \
    if (rem >= 16) {                                                         \
      const int* rb = &ridbuf[wv][(G) * SLOT_CAP + base + half];             \
      f4_t v0, v1, v2, v3, v4, v5, v6, v7;                                   \
      v0 = ld4(x + ((long long)rb[0] << 7) + coff);                          \
      v1 = ld4(x + ((long long)rb[2] << 7) + coff);                          \
      v2 = ld4(x + ((long long)rb[4] << 7) + coff);                          \
      v3 = ld4(x + ((long long)rb[6] << 7) + coff);                          \
      v4 = ld4(x + ((long long)rb[8] << 7) + coff);                          \
      v5 = ld4(x + ((long long)rb[10] << 7) + coff);                         \
      v6 = ld4(x + ((long long)rb[12] << 7) + coff);                         \
      v7 = ld4(x + ((long long)rb[14] << 7) + coff);                         \
      acc += v0; acc += v1; acc += v2; acc += v3;                            \
      acc += v4; acc += v5; acc += v6; acc += v7;                            \
      base += 16; rem -= 16;                                                 \
    }                                                                        \
    if (rem > 0) {                                                           \
      _Pragma("unroll") for (int u = 0; u < 8; ++u) {                        \
        int p = base + 2 * u + half;                                         \
        if (p < CG) {                                                        \
          int r = ridbuf[wv][(G) * SLOT_CAP + p];                            \
          acc2 += ld4(x + ((long long)r << 7) + coff);                       \
        }                                                                    \
      }                                                                      \
    }                                                                        \
    acc += acc2;                                                             \
    f4_t oth;                                                                \
    oth.x = __shfl(acc.x, lane ^ 32);                                        \
    oth.y = __shfl(acc.y, lane ^ 32);                                        \
    oth.z = __shfl(acc.z, lane ^ 32);                                        \
    oth.w = __shfl(acc.w, lane ^ 32);                                        \
    acc += oth;                                                              \
    if (!half && s0 + (G) < S) {                                             \
      *reinterpret_cast<f4_t*>(pooled + ((long long)(s0 + (G)) << 7) + coff) = acc; \
    }                                                                        \
  }

  DO_SEG(0, c0)
  DO_SEG(1, c1)
  DO_SEG(2, c2)
  DO_SEG(3, c3)
#undef DO_SEG
}

// ---------------------------------------------------------------------------
// K3: overflow fixup (after gather, before transform -> race-free).
// ---------------------------------------------------------------------------
__global__ __launch_bounds__(128) void fixup_kernel(
    const int* __restrict__ ov_count,
    const int* __restrict__ ovs, const int* __restrict__ ovr,
    const float* __restrict__ x,
    float* __restrict__ pooled) {
  int n = *ov_count;
  for (int k = blockIdx.x; k < n; k += gridDim.x) {
    int s = ovs[k];
    long long r = ovr[k];
    int c = threadIdx.x;
    atomicAdd(&pooled[(long long)s * D_DIM + c], x[r * D_DIM + c]);
  }
}

// ---------------------------------------------------------------------------
// K4: transform (known-good 2-row version, VGPR ~64, no spills).
// out[s][j] = b[j] + sum_d pooled[s][d] * W[j][d].
// ---------------------------------------------------------------------------
__global__ __launch_bounds__(256) void transform_kernel(
    const float* __restrict__ pooled,
    const float* __restrict__ W,      // [128,128] row-major [out][in]
    const float* __restrict__ b,
    float* __restrict__ out, int S) {
  __shared__ float Wt[D_DIM][D_DIM + 1];  // Wt[d][j] = W[j][d]
  int t = threadIdx.x;
  for (int f = t; f < D_DIM * D_DIM; f += 256)
    Wt[f & (D_DIM - 1)][f >> 7] = W[f];
  __syncthreads();

  int lane = t & 63;
  int wv = t >> 6;
  float2 bb = *reinterpret_cast<const float2*>(&b[2 * lane]);
  int stride = gridDim.x * 4 * 2;

  for (int s0 = (blockIdx.x * 4 + wv) * 2; s0 < S; s0 += stride) {
    float2 rv0 = *reinterpret_cast<const float2*>(&pooled[(long long)s0 * D_DIM + 2 * lane]);
    bool has1 = (s0 + 1) < S;
    float2 rv1 = has1
        ? *reinterpret_cast<const float2*>(&pooled[(long long)(s0 + 1) * D_DIM + 2 * lane])
        : make_float2(0.f, 0.f);
    float o0x = bb.x, o0y = bb.y, o1x = bb.x, o1y = bb.y;
#pragma unroll
    for (int k = 0; k < 64; ++k) {
      float p00 = __shfl(rv0.x, k);
      float p01 = __shfl(rv0.y, k);
      float p10 = __shfl(rv1.x, k);
      float p11 = __shfl(rv1.y, k);
      float2 w0 = *reinterpret_cast<const float2*>(&Wt[2 * k][2 * lane]);
      float2 w1 = *reinterpret_cast<const float2*>(&Wt[2 * k + 1][2 * lane]);
      o0x += p00 * w0.x + p01 * w1.x;
      o0y += p00 * w0.y + p01 * w1.y;
      o1x += p10 * w0.x + p11 * w1.x;
      o1y += p10 * w0.y + p11 * w1.y;
    }
    *reinterpret_cast<float2*>(&out[(long long)s0 * D_DIM + 2 * lane]) =
        make_float2(o0x, o0y);
    if (has1)
      *reinterpret_cast<float2*>(&out[(long long)(s0 + 1) * D_DIM + 2 * lane]) =
          make_float2(o1x, o1y);
  }
}

extern "C" void kernel_launch(void* const* d_in, const int* in_sizes, int n_in,
                              void* d_out, int out_size, void* d_ws, size_t ws_size,
                              hipStream_t stream) {
  const float* x = (const float*)d_in[0];
  const int* idx = (const int*)d_in[1];
  const float* W = (const float*)d_in[3];
  const float* b = (const float*)d_in[4];
  float* out = (float*)d_out;

  int N = in_sizes[0] / D_DIM;
  int S = out_size / D_DIM;

  // ws layout: fill[S] | ov_count[4] | slots[S*128] | ovs[N] | ovr[N] | pooled[S*128]
  int* fill = (int*)d_ws;
  int* ov_count = fill + S;
  int* slots = fill + S + 4;
  int* ovs = slots + (long long)S * SLOT_CAP;
  int* ovr = ovs + N;
  float* pooled = (float*)(ovr + N);

  hipMemsetAsync(fill, 0, (size_t)(S + 4) * sizeof(int), stream);

  int n4 = N / 4;
  scatter_slots_kernel<<<4096, 256, 0, stream>>>((const int4*)idx, fill, slots,
                                                 ov_count, ovs, ovr, n4);
  gather_reduce_kernel<<<(S + 15) / 16, 256, 0, stream>>>(x, slots, fill,
                                                          pooled, S);
  fixup_kernel<<<256, 128, 0, stream>>>(ov_count, ovs, ovr, x, pooled);
  transform_kernel<<<2048, 256, 0, stream>>>(pooled, W, b, out, S);
}

// Round 10
// 1008.454 us; speedup vs baseline: 1.0536x; 1.0536x over previous
//
#include <hip/hip_runtime.h>

#define D_DIM 128
#define SLOT_CAP 128

typedef float f4_t __attribute__((ext_vector_type(4)));

// NT load for the x stream: A/B (rounds 8 vs 9) measured NT = -50us (~5%).
// x is a read-once 2 GB stream; NT avoids displacing slots/pooled from L2/LLC.
__device__ __forceinline__ f4_t nt_load4(const float* p) {
  return __builtin_nontemporal_load(reinterpret_cast<const f4_t*>(p));
}

// ---------------------------------------------------------------------------
// K1: single-pass scatter into fixed-capacity per-segment slot lists.
// ---------------------------------------------------------------------------
__global__ __launch_bounds__(256) void scatter_slots_kernel(
    const int4* __restrict__ idx4,
    int* __restrict__ fill,         // [S]
    int* __restrict__ slots,        // [S*SLOT_CAP]
    int* __restrict__ ov_count,
    int* __restrict__ ovs, int* __restrict__ ovr,
    int n4) {
  int stride = gridDim.x * blockDim.x;
  for (int i = blockIdx.x * blockDim.x + threadIdx.x; i < n4; i += stride) {
    int4 v = idx4[i];
    int r = i * 4;
    int p0 = atomicAdd(&fill[v.x], 1);
    int p1 = atomicAdd(&fill[v.y], 1);
    int p2 = atomicAdd(&fill[v.z], 1);
    int p3 = atomicAdd(&fill[v.w], 1);
    if (p0 < SLOT_CAP) slots[v.x * SLOT_CAP + p0] = r;
    else { int o = atomicAdd(ov_count, 1); ovs[o] = v.x; ovr[o] = r; }
    if (p1 < SLOT_CAP) slots[v.y * SLOT_CAP + p1] = r + 1;
    else { int o = atomicAdd(ov_count, 1); ovs[o] = v.y; ovr[o] = r + 1; }
    if (p2 < SLOT_CAP) slots[v.z * SLOT_CAP + p2] = r + 2;
    else { int o = atomicAdd(ov_count, 1); ovs[o] = v.z; ovr[o] = r + 2; }
    if (p3 < SLOT_CAP) slots[v.w * SLOT_CAP + p3] = r + 3;
    else { int o = atomicAdd(ov_count, 1); ovs[o] = v.w; ovr[o] = r + 3; }
  }
}

// ---------------------------------------------------------------------------
// K2: gather-reduce. One wave owns 4 CONTIGUOUS segments.
// 32-row double-groups: 16 float4 loads in flight, two independent
// accumulators; then one 16-row group; then predicated 8-row tail.
// Measured insensitive to deeper ILP / occupancy tuning -> at the
// random-512B fetch wall (~2.7 TB/s effective).
// ---------------------------------------------------------------------------
__global__ __launch_bounds__(256, 5) void gather_reduce_kernel(
    const float* __restrict__ x,
    const int* __restrict__ slots,
    const int* __restrict__ fill,
    float* __restrict__ pooled,      // [S,128]
    int S) {
  __shared__ int ridbuf[4][4 * SLOT_CAP];  // 8 KB
  int t = threadIdx.x;
  int lane = t & 63;
  int wv = t >> 6;
  int half = lane >> 5;
  int coff = (lane & 31) << 2;
  int s0 = (blockIdx.x * 4 + wv) * 4;
  if (s0 >= S) return;

  int c0, c1, c2, c3;
  if (s0 + 3 < S) {
    int4 f = *reinterpret_cast<const int4*>(fill + s0);
    c0 = min(f.x, SLOT_CAP); c1 = min(f.y, SLOT_CAP);
    c2 = min(f.z, SLOT_CAP); c3 = min(f.w, SLOT_CAP);
    int4* rb4 = reinterpret_cast<int4*>(ridbuf[wv]);
    const int4* sp4 = reinterpret_cast<const int4*>(slots) + s0 * (SLOT_CAP / 4);
    rb4[lane] = sp4[lane];
    rb4[lane + 64] = sp4[lane + 64];
  } else {
    c0 = (s0 + 0 < S) ? min(fill[s0 + 0], SLOT_CAP) : 0;
    c1 = (s0 + 1 < S) ? min(fill[s0 + 1], SLOT_CAP) : 0;
    c2 = (s0 + 2 < S) ? min(fill[s0 + 2], SLOT_CAP) : 0;
    c3 = (s0 + 3 < S) ? min(fill[s0 + 3], SLOT_CAP) : 0;
    for (int g = 0; g < 4; ++g) {
      int c = g == 0 ? c0 : g == 1 ? c1 : g == 2 ? c2 : c3;
      if (s0 + g < S) {
        const int* sp = slots + (long long)(s0 + g) * SLOT_CAP;
        if (lane < c) ridbuf[wv][g * SLOT_CAP + lane] = sp[lane];
        if (lane + 64 < c) ridbuf[wv][g * SLOT_CAP + lane + 64] = sp[lane + 64];
      }
    }
  }

#define DO_SEG(G, CG)                                                        \
  {                                                                          \
    f4_t acc = {0.f, 0.f, 0.f, 0.f};                                         \
    f4_t acc2 = {0.f, 0.f, 0.f, 0.f};                                        \
    int full32 = CG & ~31;                                                   \
    for (int base = 0; base < full32; base += 32) {                          \
      f4_t v0, v1, v2, v3, v4, v5, v6, v7;                                   \
      f4_t w0, w1, w2, w3, w4, w5, w6, w7;                                   \
      const int* rb = &ridbuf[wv][(G) * SLOT_CAP + base + half];             \
      v0 = nt_load4(x + ((long long)rb[0] << 7) + coff);                     \
      v1 = nt_load4(x + ((long long)rb[2] << 7) + coff);                     \
      v2 = nt_load4(x + ((long long)rb[4] << 7) + coff);                     \
      v3 = nt_load4(x + ((long long)rb[6] << 7) + coff);                     \
      v4 = nt_load4(x + ((long long)rb[8] << 7) + coff);                     \
      v5 = nt_load4(x + ((long long)rb[10] << 7) + coff);                    \
      v6 = nt_load4(x + ((long long)rb[12] << 7) + coff);                    \
      v7 = nt_load4(x + ((long long)rb[14] << 7) + coff);                    \
      w0 = nt_load4(x + ((long long)rb[16] << 7) + coff);                    \
      w1 = nt_load4(x + ((long long)rb[18] << 7) + coff);                    \
      w2 = nt_load4(x + ((long long)rb[20] << 7) + coff);                    \
      w3 = nt_load4(x + ((long long)rb[22] << 7) + coff);                    \
      w4 = nt_load4(x + ((long long)rb[24] << 7) + coff);                    \
      w5 = nt_load4(x + ((long long)rb[26] << 7) + coff);                    \
      w6 = nt_load4(x + ((long long)rb[28] << 7) + coff);                    \
      w7 = nt_load4(x + ((long long)rb[30] << 7) + coff);                    \
      acc += v0; acc += v1; acc += v2; acc += v3;                            \
      acc += v4; acc += v5; acc += v6; acc += v7;                            \
      acc2 += w0; acc2 += w1; acc2 += w2; acc2 += w3;                        \
      acc2 += w4; acc2 += w5; acc2 += w6; acc2 += w7;                        \
    }                                                                        \
    int base = full32;                                                       \
    int rem = CG - full32;                                                   \
    if (rem >= 16) {                                                         \
      const int* rb = &ridbuf[wv][(G) * SLOT_CAP + base + half];             \
      f4_t v0, v1, v2, v3, v4, v5, v6, v7;                                   \
      v0 = nt_load4(x + ((long long)rb[0] << 7) + coff);                     \
      v1 = nt_load4(x + ((long long)rb[2] << 7) + coff);                     \
      v2 = nt_load4(x + ((long long)rb[4] << 7) + coff);                     \
      v3 = nt_load4(x + ((long long)rb[6] << 7) + coff);                     \
      v4 = nt_load4(x + ((long long)rb[8] << 7) + coff);                     \
      v5 = nt_load4(x + ((long long)rb[10] << 7) + coff);                    \
      v6 = nt_load4(x + ((long long)rb[12] << 7) + coff);                    \
      v7 = nt_load4(x + ((long long)rb[14] << 7) + coff);                    \
      acc += v0; acc += v1; acc += v2; acc += v3;                            \
      acc += v4; acc += v5; acc += v6; acc += v7;                            \
      base += 16; rem -= 16;                                                 \
    }                                                                        \
    if (rem > 0) {                                                           \
      _Pragma("unroll") for (int u = 0; u < 8; ++u) {                        \
        int p = base + 2 * u + half;                                         \
        if (p < CG) {                                                        \
          int r = ridbuf[wv][(G) * SLOT_CAP + p];                            \
          acc2 += nt_load4(x + ((long long)r << 7) + coff);                  \
        }                                                                    \
      }                                                                      \
    }                                                                        \
    acc += acc2;                                                             \
    f4_t oth;                                                                \
    oth.x = __shfl(acc.x, lane ^ 32);                                        \
    oth.y = __shfl(acc.y, lane ^ 32);                                        \
    oth.z = __shfl(acc.z, lane ^ 32);                                        \
    oth.w = __shfl(acc.w, lane ^ 32);                                        \
    acc += oth;                                                              \
    if (!half && s0 + (G) < S) {                                             \
      *reinterpret_cast<f4_t*>(pooled + ((long long)(s0 + (G)) << 7) + coff) = acc; \
    }                                                                        \
  }

  DO_SEG(0, c0)
  DO_SEG(1, c1)
  DO_SEG(2, c2)
  DO_SEG(3, c3)
#undef DO_SEG
}

// ---------------------------------------------------------------------------
// K3: overflow fixup (after gather, before transform -> race-free).
// ---------------------------------------------------------------------------
__global__ __launch_bounds__(128) void fixup_kernel(
    const int* __restrict__ ov_count,
    const int* __restrict__ ovs, const int* __restrict__ ovr,
    const float* __restrict__ x,
    float* __restrict__ pooled) {
  int n = *ov_count;
  for (int k = blockIdx.x; k < n; k += gridDim.x) {
    int s = ovs[k];
    long long r = ovr[k];
    int c = threadIdx.x;
    atomicAdd(&pooled[(long long)s * D_DIM + c], x[r * D_DIM + c]);
  }
}

// ---------------------------------------------------------------------------
// K4: transform (known-good 2-row version, VGPR ~64, no spills).
// out[s][j] = b[j] + sum_d pooled[s][d] * W[j][d].
// ---------------------------------------------------------------------------
__global__ __launch_bounds__(256) void transform_kernel(
    const float* __restrict__ pooled,
    const float* __restrict__ W,      // [128,128] row-major [out][in]
    const float* __restrict__ b,
    float* __restrict__ out, int S) {
  __shared__ float Wt[D_DIM][D_DIM + 1];  // Wt[d][j] = W[j][d]
  int t = threadIdx.x;
  for (int f = t; f < D_DIM * D_DIM; f += 256)
    Wt[f & (D_DIM - 1)][f >> 7] = W[f];
  __syncthreads();

  int lane = t & 63;
  int wv = t >> 6;
  float2 bb = *reinterpret_cast<const float2*>(&b[2 * lane]);
  int stride = gridDim.x * 4 * 2;

  for (int s0 = (blockIdx.x * 4 + wv) * 2; s0 < S; s0 += stride) {
    float2 rv0 = *reinterpret_cast<const float2*>(&pooled[(long long)s0 * D_DIM + 2 * lane]);
    bool has1 = (s0 + 1) < S;
    float2 rv1 = has1
        ? *reinterpret_cast<const float2*>(&pooled[(long long)(s0 + 1) * D_DIM + 2 * lane])
        : make_float2(0.f, 0.f);
    float o0x = bb.x, o0y = bb.y, o1x = bb.x, o1y = bb.y;
#pragma unroll
    for (int k = 0; k < 64; ++k) {
      float p00 = __shfl(rv0.x, k);
      float p01 = __shfl(rv0.y, k);
      float p10 = __shfl(rv1.x, k);
      float p11 = __shfl(rv1.y, k);
      float2 w0 = *reinterpret_cast<const float2*>(&Wt[2 * k][2 * lane]);
      float2 w1 = *reinterpret_cast<const float2*>(&Wt[2 * k + 1][2 * lane]);
      o0x += p00 * w0.x + p01 * w1.x;
      o0y += p00 * w0.y + p01 * w1.y;
      o1x += p10 * w0.x + p11 * w1.x;
      o1y += p10 * w0.y + p11 * w1.y;
    }
    *reinterpret_cast<float2*>(&out[(long long)s0 * D_DIM + 2 * lane]) =
        make_float2(o0x, o0y);
    if (has1)
      *reinterpret_cast<float2*>(&out[(long long)(s0 + 1) * D_DIM + 2 * lane]) =
          make_float2(o1x, o1y);
  }
}

extern "C" void kernel_launch(void* const* d_in, const int* in_sizes, int n_in,
                              void* d_out, int out_size, void* d_ws, size_t ws_size,
                              hipStream_t stream) {
  const float* x = (const float*)d_in[0];
  const int* idx = (const int*)d_in[1];
  const float* W = (const float*)d_in[3];
  const float* b = (const float*)d_in[4];
  float* out = (float*)d_out;

  int N = in_sizes[0] / D_DIM;
  int S = out_size / D_DIM;

  // ws layout: fill[S] | ov_count[4] | slots[S*128] | ovs[N] | ovr[N] | pooled[S*128]
  int* fill = (int*)d_ws;
  int* ov_count = fill + S;
  int* slots = fill + S + 4;
  int* ovs = slots + (long long)S * SLOT_CAP;
  int* ovr = ovs + N;
  float* pooled = (float*)(ovr + N);

  hipMemsetAsync(fill, 0, (size_t)(S + 4) * sizeof(int), stream);

  int n4 = N / 4;
  scatter_slots_kernel<<<4096, 256, 0, stream>>>((const int4*)idx, fill, slots,
                                                 ov_count, ovs, ovr, n4);
  gather_reduce_kernel<<<(S + 15) / 16, 256, 0, stream>>>(x, slots, fill,
                                                          pooled, S);
  fixup_kernel<<<256, 128, 0, stream>>>(ov_count, ovs, ovr, x, pooled);
  transform_kernel<<<2048, 256, 0, stream>>>(pooled, W, b, out, S);
}